// Round 1
// baseline (327.223 us; speedup 1.0000x reference)
//
#include <hip/hip_runtime.h>

// PatchMask: out[b,c,h,w] = x[b,c,h,w] * keep_mask[b, h/16, w/16]
// x: fp32 [64,3,512,512]  (50,331,648 elems, 192 MiB)
// keep_mask: bool->int32 [64,32,32]
//
// Memory-bound elementwise pass. Key change vs previous version:
// masked patches (35%) never need their x values — make the x load
// conditional on the mask so exec-masked lanes issue no fetch. A patch
// row is 64 contiguous bytes = 4 consecutive float4 lanes, so skipped
// segments are whole 64B sectors. Expected FETCH_SIZE drop: 12-35%
// depending on HBM fetch granularity (128B line vs 64B sector).
// Store is nontemporal: out is never re-read; avoid L2 write-allocate
// pollution so the mask (256 KiB) stays L2-hot.

#define W_DIM 512
#define H_DIM 512
#define CH 3
#define PATCH 16

typedef float f32x4 __attribute__((ext_vector_type(4)));

__global__ __launch_bounds__(256) void PatchMask_kernel(
    const f32x4* __restrict__ x,
    const int* __restrict__ mask,
    f32x4* __restrict__ out,
    int n4)
{
    int i = blockIdx.x * blockDim.x + threadIdx.x;
    if (i >= n4) return;

    int e = i << 2;                 // element index (max ~50.3M, fits int32)
    int w = e & (W_DIM - 1);        // 512 = 2^9
    int h = (e >> 9) & (H_DIM - 1);
    int bc = e >> 18;               // b*3 + c  (512*512 = 2^18)
    int b = bc / CH;                // compiler emits magic-mul

    // mask is [B, 32, 32]
    int mi = (b << 10) + ((h >> 4) << 5) + (w >> 4);

    f32x4 v = (f32x4)(0.f, 0.f, 0.f, 0.f);
    if (mask[mi] != 0) {
        // Only kept patches fetch x; masked lanes issue no memory request.
        v = x[i];
    }
    __builtin_nontemporal_store(v, &out[i]);
}

extern "C" void kernel_launch(void* const* d_in, const int* in_sizes, int n_in,
                              void* d_out, int out_size, void* d_ws, size_t ws_size,
                              hipStream_t stream) {
    const f32x4* x    = (const f32x4*)d_in[0];
    const int* mask   = (const int*)d_in[1];
    f32x4* out        = (f32x4*)d_out;

    int n4 = out_size >> 2;                      // 12,582,912 float4s
    int block = 256;
    int grid = (n4 + block - 1) / block;         // 49,152

    PatchMask_kernel<<<grid, block, 0, stream>>>(x, mask, out, n4);
}

// Round 2
// 320.757 us; speedup vs baseline: 1.0202x; 1.0202x over previous
//
#include <hip/hip_runtime.h>

// PatchMask: out[b,c,h,w] = x[b,c,h,w] * keep_mask[b, h/16, w/16]
// x: fp32 [64,3,512,512]  (50,331,648 elems, 192 MiB)
// keep_mask: bool->int32 [64,32,32]  (256 KiB, L2-resident)
//
// Memory-bound elementwise pass at the HBM roofline:
//   - float4 per thread, fully coalesced (1 KiB per wave per instr)
//   - mask and x loads issue INDEPENDENTLY (no dependent-load chain;
//     round-1 experiment showed conditional fetch-skip is neutral-to-
//     negative: 128B TCC lines span 2 patches so skips are rare, and
//     the mask->x serialization costs MLP)
//   - mask lookup is 1 int per 4 consecutive w-pixels (one 16-wide
//     patch row spans exactly 4 float4 lanes)
// Traffic: 192 MiB read + 192 MiB write + mask ~= 402 MB; at the
// 6.6 TB/s demonstrated ceiling -> ~61 us kernel floor.

#define W_DIM 512
#define H_DIM 512
#define CH 3
#define PATCH 16

__global__ __launch_bounds__(256) void PatchMask_kernel(
    const float4* __restrict__ x,
    const int* __restrict__ mask,
    float4* __restrict__ out,
    int n4)
{
    int i = blockIdx.x * blockDim.x + threadIdx.x;
    if (i >= n4) return;

    int e = i << 2;                 // element index (max ~50.3M, fits int32)
    int w = e & (W_DIM - 1);        // 512 = 2^9
    int h = (e >> 9) & (H_DIM - 1);
    int bc = e >> 18;               // b*3 + c  (512*512 = 2^18)
    int b = bc / CH;                // compiler emits magic-mul

    // mask is [B, 32, 32]
    int mi = (b << 10) + ((h >> 4) << 5) + (w >> 4);

    float4 v = x[i];                // issues in parallel with mask load
    if (mask[mi] == 0) {
        v.x = 0.f; v.y = 0.f; v.z = 0.f; v.w = 0.f;
    }
    out[i] = v;
}

extern "C" void kernel_launch(void* const* d_in, const int* in_sizes, int n_in,
                              void* d_out, int out_size, void* d_ws, size_t ws_size,
                              hipStream_t stream) {
    const float4* x   = (const float4*)d_in[0];
    const int* mask   = (const int*)d_in[1];
    float4* out       = (float4*)d_out;

    int n4 = out_size >> 2;                      // 12,582,912 float4s
    int block = 256;
    int grid = (n4 + block - 1) / block;         // 49,152

    PatchMask_kernel<<<grid, block, 0, stream>>>(x, mask, out, n4);
}